// Round 21
// baseline (161.421 us; speedup 1.0000x reference)
//
#include <hip/hip_runtime.h>
#include <hip/hip_bf16.h>

// ---------------- problem constants ----------------
#define T_LEN 1048576
#define FL    1024
#define PADL  512
#define HOP   256
#define NFR   4097            // frames per batch
#define NB    8
#define NSEG  4100            // segments per batch
#define MROWS 1028            // 2*(513+1) interleaved re/im rows, k=0..513
#define MPAD  1152            // padded C-matrix rows
#define MTL   18              // M-tiles (stride 30 k = 60 rows; tile = 64 rows)
#define FTL   34              // frame-tiles per batch (stride 124 -> aligned stores)
#define NTL   272             // FTL*NB
#define NWG2  4896            // MTL*NTL (divisible by 8)

typedef __bf16 bf16x8 __attribute__((ext_vector_type(8)));
typedef float  f32x4  __attribute__((ext_vector_type(4)));

__device__ __forceinline__ void gload16(const __hip_bfloat16* g, void* l) {
  __builtin_amdgcn_global_load_lds(
      (const __attribute__((address_space(1))) unsigned int*)g,
      (__attribute__((address_space(3))) unsigned int*)l, 16, 0, 0);
}

// ---------------- prep: build segment-DFT matrix only ----------------
__global__ __launch_bounds__(256) void prep_cmat(__hip_bfloat16* __restrict__ cm) {
  const int idx = blockIdx.x * 256 + threadIdx.x;   // over MPAD*256
  if (idx >= MPAD * 256) return;
  const int row = idx >> 8, r = idx & 255;
  float v = 0.f;
  if (row < MROWS) {
    const int k = row >> 1;
    const int ph = (k * r) & 1023;
    const float ang = (float)ph * 6.2831853071795864769f / 1024.f;
    v = (row & 1) ? -sinf(ang) : cosf(ang);
  }
  cm[idx] = __float2bfloat16(v);
}

// ---------------- fused pad/convert + segment-GEMM + two-pass combine ----------------
// Waves 0-3: GEMM compute (2Mx2N over 64x128, acc[2][4], operand-swapped
// MFMA so acc f32x4 = 4 consecutive frames of one cm-row). Waves 4-7:
// producers: A via gload_lds from cmat; B loaded DIRECTLY from x (f32),
// reflect-pad + bf16 cvt in-kernel (no xp pre-pass), slot-PAIR granularity
// (8 named float4, 32 VGPR live), one VMC(0) drain per pair (edge-divergence
// makes counted vmcnt invalid). 4 sub-slots x {4KB A + 8KB B} = 48 KB.
__global__ __launch_bounds__(512, 3) void stft_fgemm(
    const __hip_bfloat16* __restrict__ Cm,  // [MPAD][256]
    const float* __restrict__ x,            // [NB][T_LEN]
    float* __restrict__ out) {              // [NB][1026][4097]
  __shared__ char ldsraw[49152];            // staging 48 KB; U (33.8 KB) aliases
  __hip_bfloat16* stg = (__hip_bfloat16*)ldsraw;
  float* Ub = (float*)ldsraw;

  // XCD swizzle (4896 % 8 == 0); consecutive wg share the N-tile (B reuse)
  const int orig = blockIdx.x;
  const int wg = (orig & 7) * (NWG2 / 8) + (orig >> 3);
  const int mt = wg % MTL;
  const int nt = wg / MTL;
  const int b = nt / FTL, ft = nt % FTL;
  const int gb = ft * 124;                  // segment/frame base (mod 4 == 0)
  const int RB = mt * 60;                   // C-matrix row base (stride 30 k)
  const int kbase = 30 * mt;                // kappa of local row-pair 0

  const int tid = threadIdx.x;
  const int w = tid >> 6, l = tid & 63;     // 8 waves
  const bool isProd = w >= 4;
  const int cw = w & 3;                     // role-local wave id
  const int wm = cw >> 1, wn = cw & 1;      // compute: 2M x 2N (32 rows x 64 frames)

  // ---- staging addressing (producers; pre-swizzled source, linear dest) ----
  const int g_log = (l & 3) ^ ((l >> 3) & 3);
  const int srow = l >> 2;
  const __hip_bfloat16* aB0 = Cm + (size_t)(RB + cw * 16 + srow) * 256 + g_log * 8;
  const float* __restrict__ xb = x + (size_t)b * T_LEN;
  long boff[2];                             // interior f32 offset into xb
  int edgeC[2];                             // reflect constant for edge segs
  bool intr[2];
#pragma unroll
  for (int j = 0; j < 2; ++j) {
    int g = gb + (cw * 2 + j) * 16 + srow;
    if (g > NSEG - 1) g = NSEG - 1;         // clamp (outputs guarded)
    intr[j] = (g >= 2 && g <= 4097);        // fully interior segment
    boff[j] = (long)g * 256 - 512 + g_log * 8;
    edgeC[j] = (g <= 1 ? 512 - g * 256 : 2097662 - g * 256) - g_log * 8;
  }

  // ---- fragment read addressing (swizzled; conflict-free) ----
  const int swz = ((l >> 4) ^ ((l >> 1) & 3)) * 8;
  const int aIdx = (wm * 32 + (l & 15)) * 32 + swz;          // + m*512
  const int bIdx = 2048 + (wn * 64 + (l & 15)) * 32 + swz;   // + n*512

  f32x4 acc[2][4] = {};

#define RDMM(S_) do {                                                        \
    bf16x8 af_[2], bf_[4];                                                   \
    _Pragma("unroll") for (int m = 0; m < 2; ++m)                            \
      af_[m] = *(const bf16x8*)(stg + (S_) * 6144 + aIdx + m * 512);         \
    _Pragma("unroll") for (int n = 0; n < 4; ++n)                            \
      bf_[n] = *(const bf16x8*)(stg + (S_) * 6144 + bIdx + n * 512);         \
    __builtin_amdgcn_s_setprio(1);                                           \
    _Pragma("unroll") for (int m = 0; m < 2; ++m)                            \
      _Pragma("unroll") for (int n = 0; n < 4; ++n)                          \
        acc[m][n] = __builtin_amdgcn_mfma_f32_16x16x32_bf16(                 \
            bf_[n], af_[m], acc[m][n], 0, 0, 0);                             \
    __builtin_amdgcn_s_setprio(0);                                           \
  } while (0)

#define BAR __builtin_amdgcn_s_barrier()
#define SB  __builtin_amdgcn_sched_barrier(0)

  if (isProd) {
#define LDBCH(j_, K0_, F0_, F1_) do {                                        \
      if (intr[j_]) {                                                        \
        F0_ = *(const float4*)&xb[boff[j_] + (K0_)];                         \
        F1_ = *(const float4*)&xb[boff[j_] + (K0_) + 4];                     \
      } else {                                                               \
        const int c0_ = edgeC[j_] - (K0_);                                   \
        F0_.x = xb[c0_];     F0_.y = xb[c0_ - 1];                            \
        F0_.z = xb[c0_ - 2]; F0_.w = xb[c0_ - 3];                            \
        F1_.x = xb[c0_ - 4]; F1_.y = xb[c0_ - 5];                            \
        F1_.z = xb[c0_ - 6]; F1_.w = xb[c0_ - 7];                            \
      }                                                                      \
    } while (0)

#define CVTWR(S_, j_, F0_, F1_) do {                                         \
      union { bf16x8 v; __hip_bfloat16 h[8]; } u_;                           \
      u_.h[0] = __float2bfloat16(F0_.x); u_.h[1] = __float2bfloat16(F0_.y);  \
      u_.h[2] = __float2bfloat16(F0_.z); u_.h[3] = __float2bfloat16(F0_.w);  \
      u_.h[4] = __float2bfloat16(F1_.x); u_.h[5] = __float2bfloat16(F1_.y);  \
      u_.h[6] = __float2bfloat16(F1_.z); u_.h[7] = __float2bfloat16(F1_.w);  \
      *(bf16x8*)(stg + (S_) * 6144 + 2048 + (cw * 2 + (j_)) * 512 + l * 8)   \
          = u_.v;                                                            \
    } while (0)

    // PAIR: stage A (async gload_lds) + B (f32 reg -> cvt -> ds_write) for
    // two sub-slots; one full vmem drain; lgkm drain before the barrier.
#define PAIR(Ka_, Kb_, Sa_, Sb_) do {                                        \
      float4 f0, f1, f2, f3, h0, h1, h2, h3;                                 \
      gload16(aB0 + (Ka_), (void*)(stg + (Sa_) * 6144 + cw * 512));          \
      gload16(aB0 + (Kb_), (void*)(stg + (Sb_) * 6144 + cw * 512));          \
      LDBCH(0, Ka_, f0, f1); LDBCH(1, Ka_, f2, f3);                          \
      LDBCH(0, Kb_, h0, h1); LDBCH(1, Kb_, h2, h3);                          \
      asm volatile("s_waitcnt vmcnt(0)" ::: "memory");                       \
      CVTWR(Sa_, 0, f0, f1); CVTWR(Sa_, 1, f2, f3);                          \
      CVTWR(Sb_, 0, h0, h1); CVTWR(Sb_, 1, h2, h3);                          \
      asm volatile("s_waitcnt lgkmcnt(0)" ::: "memory");                     \
    } while (0)

    PAIR(0, 32, 0, 1);    BAR;              // BAR0: slots 0,1 ready
    SB; PAIR(64, 96, 2, 3);   BAR;          // BAR1: slots 2,3 ready
    SB; PAIR(128, 160, 0, 1); BAR;          // BAR2: new 0,1 ready
    SB; PAIR(192, 224, 2, 3); BAR;          // BAR3: new 2,3 ready
#undef PAIR
#undef CVTWR
#undef LDBCH
  } else {
    BAR;
    SB; RDMM(0); RDMM(1); BAR;
    SB; RDMM(2); RDMM(3); BAR;
    SB; RDMM(0); RDMM(1); BAR;
    SB; RDMM(2); RDMM(3);
  }
  __syncthreads();                          // staging dead; alias as f32 U

#undef SB
#undef RDMM

  // ---- write U tile to LDS as f32 [row][col] stride 132, b128 stores ----
  if (!isProd) {
    const int cb = l & 15, fb4 = (l >> 4) * 4;
#pragma unroll
    for (int m = 0; m < 2; ++m)
#pragma unroll
      for (int n = 0; n < 4; ++n) {
        const int row = wm * 32 + m * 16 + cb;
        const int col = wn * 64 + n * 16 + fb4;
        *(f32x4*)(Ub + row * 132 + col) = acc[m][n];
      }
  }
  __syncthreads();

  // ---- pass A: Z[k,f] = sum_q (-i)^(kq) U[k,f+q]; all 8 waves, 2 cells ----
  f32x4 zre[2], zim[2];
#pragma unroll
  for (int it = 0; it < 2; ++it) {
    const int cell = it * 512 + tid;
    const int rp = cell >> 5;               // 0..31
    const int g4 = (cell & 31) * 4;
    const float* rr = Ub + (rp * 2) * 132 + g4;
    const f32x4 r0 = *(const f32x4*)rr;
    const f32x4 r1 = *(const f32x4*)(rr + 4);
    const f32x4 i0 = *(const f32x4*)(rr + 132);
    const f32x4 i1 = *(const f32x4*)(rr + 136);
    const float ur[8] = {r0[0], r0[1], r0[2], r0[3], r1[0], r1[1], r1[2], r1[3]};
    const float ui[8] = {i0[0], i0[1], i0[2], i0[3], i1[0], i1[1], i1[2], i1[3]};
    const int cls = (kbase + rp) & 3;
    const float s = (cls & 2) ? -1.f : 1.f;
    const bool odd = cls & 1;
    f32x4 zr, zi;
#pragma unroll
    for (int j = 0; j < 4; ++j) {
      const float p  = ur[j] - ur[j + 2], q  = ur[j] + ur[j + 2];
      const float pi = ui[j] - ui[j + 2], qi = ui[j] + ui[j + 2];
      const float rm = ur[j + 1] - ur[j + 3], rp_ = ur[j + 1] + ur[j + 3];
      const float sm = ui[j + 1] - ui[j + 3], sp = ui[j + 1] + ui[j + 3];
      zr[j] = odd ? (p + s * sm) : (q + s * rp_);
      zi[j] = odd ? (pi - s * rm) : (qi + s * sp);
    }
    zre[it] = zr; zim[it] = zi;
  }
  __syncthreads();
#pragma unroll
  for (int it = 0; it < 2; ++it) {
    const int cell = it * 512 + tid;
    const int rp = cell >> 5;
    const int g4 = (cell & 31) * 4;
    *(f32x4*)(Ub + (rp * 2) * 132 + g4) = zre[it];
    *(f32x4*)(Ub + (rp * 2 + 1) * 132 + g4) = zim[it];
  }
  __syncthreads();

  // ---- pass B: Y[k] = 0.5 Z[k] - 0.25 (Z[k-1]+Z[k+1]); Z[k] from regs ----
  const size_t ob = (size_t)b * 1026 * 4097;
#pragma unroll
  for (int it = 0; it < 2; ++it) {
    const int cell = it * 512 + tid;
    const int rp = cell >> 5;
    const int g4 = (cell & 31) * 4;
    const int k = kbase + rp;
    const int f0 = gb + g4;
    if (g4 <= 120) {
      if (rp >= 1 && rp <= 30 && k <= 512) {
        const float* zp = Ub + rp * 264 + g4;         // this row-pair base
        const f32x4 zmr = *(const f32x4*)(zp - 264);
        const f32x4 zmi = *(const f32x4*)(zp - 132);
        const f32x4 zpr = *(const f32x4*)(zp + 264);
        const f32x4 zpi = *(const f32x4*)(zp + 396);
        const f32x4 Yr = 0.5f * zre[it] - 0.25f * (zmr + zpr);
        const f32x4 Yi = 0.5f * zim[it] - 0.25f * (zmi + zpi);
        float* orow = out + ob + (size_t)k * NFR;
        float* irow = out + ob + (size_t)(513 + k) * NFR;
        if (f0 + 3 <= NFR - 1) {
          *(f32x4*)&orow[f0] = Yr;
          *(f32x4*)&irow[f0] = Yi;
        } else {
#pragma unroll
          for (int j = 0; j < 4; ++j)
            if (f0 + j <= NFR - 1) { orow[f0 + j] = Yr[j]; irow[f0 + j] = Yi[j]; }
        }
      } else if (mt == 0 && rp == 0) {
        // k = 0 edge: Yr = 0.5 Zr0 - 0.5 Zr1, Yi = 0.5 Zi0
        const f32x4 z1r = *(const f32x4*)(Ub + 264 + g4);
        const f32x4 Yr = 0.5f * zre[it] - 0.5f * z1r;
        const f32x4 Yi = 0.5f * zim[it];
        if (f0 + 3 <= NFR - 1) {
          *(f32x4*)&out[ob + f0] = Yr;
          *(f32x4*)&out[ob + (size_t)513 * NFR + f0] = Yi;
        } else {
#pragma unroll
          for (int j = 0; j < 4; ++j)
            if (f0 + j <= NFR - 1) {
              out[ob + f0 + j] = Yr[j];
              out[ob + (size_t)513 * NFR + f0 + j] = Yi[j];
            }
        }
      }
    }
  }
#undef BAR
}

extern "C" void kernel_launch(void* const* d_in, const int* in_sizes, int n_in,
                              void* d_out, int out_size, void* d_ws, size_t ws_size,
                              hipStream_t stream) {
  const float* x = (const float*)d_in[0];       // [8, 1048576] f32
  float* out = (float*)d_out;                   // [8, 1026, 4097] f32

  __hip_bfloat16* cmat = (__hip_bfloat16*)d_ws; // MPAD*256 bf16

  prep_cmat<<<MPAD, 256, 0, stream>>>(cmat);
  stft_fgemm<<<NWG2, 512, 0, stream>>>(cmat, x, out);
}

// Round 22
// 56.398 us; speedup vs baseline: 2.8622x; 2.8622x over previous
//
#include <hip/hip_runtime.h>
#include <hip/hip_bf16.h>

// ---------------- problem constants ----------------
#define T_LEN 1048576
#define FL    1024
#define PADL  512
#define HOP   256
#define NFR   4097            // frames per batch
#define NB    8
#define XP2   1049600         // reflect-padded length per batch = 4100*256
#define NSEG  4100            // segments per batch
#define MROWS 1028            // 2*(513+1) interleaved re/im rows, k=0..513
#define MPAD  1152            // padded C-matrix rows
#define MTL   18              // M-tiles (stride 30 k = 60 rows; tile = 64 rows)
#define FTL   34              // frame-tiles per batch (stride 124 -> aligned stores)
#define NTL   272             // FTL*NB
#define NWG2  4896            // MTL*NTL (divisible by 8)
#define PADBLK 513            // pad blocks per batch
#define NPREP (PADBLK * NB + MPAD)   // 4104 + 1152 = 5256

typedef __bf16 bf16x8 __attribute__((ext_vector_type(8)));
typedef float  f32x4  __attribute__((ext_vector_type(4)));

__device__ __forceinline__ void gload16(const __hip_bfloat16* g, void* l) {
  __builtin_amdgcn_global_load_lds(
      (const __attribute__((address_space(1))) unsigned int*)g,
      (__attribute__((address_space(3))) unsigned int*)l, 16, 0, 0);
}

// ---------------- fused prep: reflect-pad/convert x + build cmat ----------------
__global__ __launch_bounds__(256) void prep(
    const float* __restrict__ x, __hip_bfloat16* __restrict__ xp,
    __hip_bfloat16* __restrict__ cm) {
  const int bid = blockIdx.x;
  if (bid < PADBLK * NB) {
    const int b = bid / PADBLK, xblk = bid % PADBLK;
    const int base = (xblk * 256 + threadIdx.x) * 8;
    if (base >= XP2) return;
    const float* __restrict__ xb = x + (size_t)b * T_LEN;
    union { bf16x8 v; __hip_bfloat16 h[8]; } o;
    if (base >= PADL && base + 8 <= PADL + T_LEN) {
      const float4 v0 = *(const float4*)&xb[base - PADL];
      const float4 v1 = *(const float4*)&xb[base - PADL + 4];
      o.h[0] = __float2bfloat16(v0.x); o.h[1] = __float2bfloat16(v0.y);
      o.h[2] = __float2bfloat16(v0.z); o.h[3] = __float2bfloat16(v0.w);
      o.h[4] = __float2bfloat16(v1.x); o.h[5] = __float2bfloat16(v1.y);
      o.h[6] = __float2bfloat16(v1.z); o.h[7] = __float2bfloat16(v1.w);
      *(bf16x8*)&xp[(size_t)b * XP2 + base] = o.v;
    } else {
      for (int e = 0; e < 8; ++e) {
        const int i = base + e;
        if (i < XP2) {
          const int t = i - PADL;
          const int idx = (t < 0) ? -t : ((t >= T_LEN) ? (2 * T_LEN - 2 - t) : t);
          xp[(size_t)b * XP2 + i] = __float2bfloat16(xb[idx]);
        }
      }
    }
  } else {
    const int idx = (bid - PADBLK * NB) * 256 + threadIdx.x;   // over MPAD*256
    if (idx >= MPAD * 256) return;
    const int row = idx >> 8, r = idx & 255;
    float v = 0.f;
    if (row < MROWS) {
      const int k = row >> 1;
      const int ph = (k * r) & 1023;
      const float ang = (float)ph * 6.2831853071795864769f / 1024.f;
      v = (row & 1) ? -sinf(ang) : cosf(ang);
    }
    cm[idx] = __float2bfloat16(v);
  }
}

// ---------------- fused segment-GEMM + combine; 64-row tiles, 3 blocks/CU ----------------
// Waves 0-3: GEMM compute (2Mx2N over 64x128, acc[2][4], operand-swapped
// MFMA so acc f32x4 = 4 consecutive frames of one cm-row). Waves 4-7:
// producers (own the vmcnt ledger). 4 sub-slots x {4KB A + 8KB B} = 48 KB.
// Combine: two-pass (pass A Z->LDS, pass B 3-tap from LDS, Z[k] from regs).
__global__ __launch_bounds__(512, 3) void stft_fgemm(
    const __hip_bfloat16* __restrict__ Cm,  // [MPAD][256]
    const __hip_bfloat16* __restrict__ X,   // [NB][XP2]
    float* __restrict__ out) {              // [NB][1026][4097]
  __shared__ char ldsraw[49152];            // staging 48 KB; U (33.8 KB) aliases
  __hip_bfloat16* stg = (__hip_bfloat16*)ldsraw;
  float* Ub = (float*)ldsraw;

  // XCD swizzle (4896 % 8 == 0); consecutive wg share the N-tile (B reuse)
  const int orig = blockIdx.x;
  const int wg = (orig & 7) * (NWG2 / 8) + (orig >> 3);
  const int mt = wg % MTL;
  const int nt = wg / MTL;
  const int b = nt / FTL, ft = nt % FTL;
  const int gb = ft * 124;                  // segment/frame base (mod 4 == 0)
  const int RB = mt * 60;                   // C-matrix row base (stride 30 k)
  const int kbase = 30 * mt;                // kappa of local row-pair 0

  const int tid = threadIdx.x;
  const int w = tid >> 6, l = tid & 63;     // 8 waves
  const bool isProd = w >= 4;
  const int cw = w & 3;                     // role-local wave id
  const int wm = cw >> 1, wn = cw & 1;      // compute: 2M x 2N (32 rows x 64 frames)

  // ---- staging addressing (producers; pre-swizzled source, linear dest) ----
  const int g_log = (l & 3) ^ ((l >> 3) & 3);
  const int srow = l >> 2;
  const __hip_bfloat16* aB0 = Cm + (size_t)(RB + cw * 16 + srow) * 256 + g_log * 8;
  const __hip_bfloat16* bB_[2];
#pragma unroll
  for (int j = 0; j < 2; ++j) {
    int g = gb + (cw * 2 + j) * 16 + srow;
    if (g > NSEG - 1) g = NSEG - 1;         // clamp (outputs guarded)
    bB_[j] = X + (size_t)b * XP2 + (size_t)g * 256 + g_log * 8;
  }

  // ---- fragment read addressing (swizzled; conflict-free) ----
  const int swz = ((l >> 4) ^ ((l >> 1) & 3)) * 8;
  const int aIdx = (wm * 32 + (l & 15)) * 32 + swz;          // + m*512
  const int bIdx = 2048 + (wn * 64 + (l & 15)) * 32 + swz;   // + n*512

  f32x4 acc[2][4] = {};

#define STAGE(K0_, S_) do {                                                  \
    gload16(aB0 + (K0_), (void*)(stg + (S_) * 6144 + cw * 512));             \
    _Pragma("unroll") for (int j = 0; j < 2; ++j)                            \
      gload16(bB_[j] + (K0_),                                                \
              (void*)(stg + (S_) * 6144 + 2048 + (cw * 2 + j) * 512));       \
  } while (0)

#define RDMM(S_) do {                                                        \
    bf16x8 af_[2], bf_[4];                                                   \
    _Pragma("unroll") for (int m = 0; m < 2; ++m)                            \
      af_[m] = *(const bf16x8*)(stg + (S_) * 6144 + aIdx + m * 512);         \
    _Pragma("unroll") for (int n = 0; n < 4; ++n)                            \
      bf_[n] = *(const bf16x8*)(stg + (S_) * 6144 + bIdx + n * 512);         \
    __builtin_amdgcn_s_setprio(1);                                           \
    _Pragma("unroll") for (int m = 0; m < 2; ++m)                            \
      _Pragma("unroll") for (int n = 0; n < 4; ++n)                          \
        acc[m][n] = __builtin_amdgcn_mfma_f32_16x16x32_bf16(                 \
            bf_[n], af_[m], acc[m][n], 0, 0, 0);                             \
    __builtin_amdgcn_s_setprio(0);                                           \
  } while (0)

#define BAR __builtin_amdgcn_s_barrier()
#define SB  __builtin_amdgcn_sched_barrier(0)
#define VMC(N_) asm volatile("s_waitcnt vmcnt(" #N_ ")" ::: "memory")

  // 4 BK=64 super-tiles over sub-slots {0,1,2,3}; producers own vmcnt.
  if (isProd) {
    STAGE(0, 0); STAGE(32, 1); STAGE(64, 2); STAGE(96, 3);
    VMC(6);  BAR;                           // sub 0,1 landed
    VMC(0);  BAR;                           // sub 2,3 landed
    SB; STAGE(128, 0); STAGE(160, 1);
    VMC(0);  BAR;                           // new 0,1 landed
    SB; STAGE(192, 2); STAGE(224, 3);
    VMC(0);  BAR;                           // new 2,3 landed
  } else {
    BAR;
    SB; RDMM(0); RDMM(1); BAR;
    SB; RDMM(2); RDMM(3); BAR;
    SB; RDMM(0); RDMM(1); BAR;
    SB; RDMM(2); RDMM(3);
  }
  __syncthreads();                          // staging dead; alias as f32 U

#undef VMC
#undef SB
#undef RDMM
#undef STAGE

  // ---- write U tile to LDS as f32 [row][col] stride 132, b128 stores ----
  if (!isProd) {
    const int cb = l & 15, fb4 = (l >> 4) * 4;
#pragma unroll
    for (int m = 0; m < 2; ++m)
#pragma unroll
      for (int n = 0; n < 4; ++n) {
        const int row = wm * 32 + m * 16 + cb;
        const int col = wn * 64 + n * 16 + fb4;
        *(f32x4*)(Ub + row * 132 + col) = acc[m][n];
      }
  }
  __syncthreads();

  // ---- pass A: Z[k,f] = sum_q (-i)^(kq) U[k,f+q]; all 8 waves, 2 cells ----
  f32x4 zre[2], zim[2];
#pragma unroll
  for (int it = 0; it < 2; ++it) {
    const int cell = it * 512 + tid;
    const int rp = cell >> 5;               // 0..31
    const int g4 = (cell & 31) * 4;
    const float* rr = Ub + (rp * 2) * 132 + g4;
    const f32x4 r0 = *(const f32x4*)rr;
    const f32x4 r1 = *(const f32x4*)(rr + 4);
    const f32x4 i0 = *(const f32x4*)(rr + 132);
    const f32x4 i1 = *(const f32x4*)(rr + 136);
    const float ur[8] = {r0[0], r0[1], r0[2], r0[3], r1[0], r1[1], r1[2], r1[3]};
    const float ui[8] = {i0[0], i0[1], i0[2], i0[3], i1[0], i1[1], i1[2], i1[3]};
    const int cls = (kbase + rp) & 3;
    const float s = (cls & 2) ? -1.f : 1.f;
    const bool odd = cls & 1;
    f32x4 zr, zi;
#pragma unroll
    for (int j = 0; j < 4; ++j) {
      const float p  = ur[j] - ur[j + 2], q  = ur[j] + ur[j + 2];
      const float pi = ui[j] - ui[j + 2], qi = ui[j] + ui[j + 2];
      const float rm = ur[j + 1] - ur[j + 3], rp_ = ur[j + 1] + ur[j + 3];
      const float sm = ui[j + 1] - ui[j + 3], sp = ui[j + 1] + ui[j + 3];
      zr[j] = odd ? (p + s * sm) : (q + s * rp_);
      zi[j] = odd ? (pi - s * rm) : (qi + s * sp);
    }
    zre[it] = zr; zim[it] = zi;
  }
  __syncthreads();
#pragma unroll
  for (int it = 0; it < 2; ++it) {
    const int cell = it * 512 + tid;
    const int rp = cell >> 5;
    const int g4 = (cell & 31) * 4;
    *(f32x4*)(Ub + (rp * 2) * 132 + g4) = zre[it];
    *(f32x4*)(Ub + (rp * 2 + 1) * 132 + g4) = zim[it];
  }
  __syncthreads();

  // ---- pass B: Y[k] = 0.5 Z[k] - 0.25 (Z[k-1]+Z[k+1]); Z[k] from regs ----
  const size_t ob = (size_t)b * 1026 * 4097;
#pragma unroll
  for (int it = 0; it < 2; ++it) {
    const int cell = it * 512 + tid;
    const int rp = cell >> 5;
    const int g4 = (cell & 31) * 4;
    const int k = kbase + rp;
    const int f0 = gb + g4;
    if (g4 <= 120) {
      if (rp >= 1 && rp <= 30 && k <= 512) {
        const float* zp = Ub + rp * 264 + g4;         // this row-pair base
        const f32x4 zmr = *(const f32x4*)(zp - 264);
        const f32x4 zmi = *(const f32x4*)(zp - 132);
        const f32x4 zpr = *(const f32x4*)(zp + 264);
        const f32x4 zpi = *(const f32x4*)(zp + 396);
        const f32x4 Yr = 0.5f * zre[it] - 0.25f * (zmr + zpr);
        const f32x4 Yi = 0.5f * zim[it] - 0.25f * (zmi + zpi);
        float* orow = out + ob + (size_t)k * NFR;
        float* irow = out + ob + (size_t)(513 + k) * NFR;
        if (f0 + 3 <= NFR - 1) {
          *(f32x4*)&orow[f0] = Yr;
          *(f32x4*)&irow[f0] = Yi;
        } else {
#pragma unroll
          for (int j = 0; j < 4; ++j)
            if (f0 + j <= NFR - 1) { orow[f0 + j] = Yr[j]; irow[f0 + j] = Yi[j]; }
        }
      } else if (mt == 0 && rp == 0) {
        // k = 0 edge: Yr = 0.5 Zr0 - 0.5 Zr1, Yi = 0.5 Zi0
        const f32x4 z1r = *(const f32x4*)(Ub + 264 + g4);
        const f32x4 Yr = 0.5f * zre[it] - 0.5f * z1r;
        const f32x4 Yi = 0.5f * zim[it];
        if (f0 + 3 <= NFR - 1) {
          *(f32x4*)&out[ob + f0] = Yr;
          *(f32x4*)&out[ob + (size_t)513 * NFR + f0] = Yi;
        } else {
#pragma unroll
          for (int j = 0; j < 4; ++j)
            if (f0 + j <= NFR - 1) {
              out[ob + f0 + j] = Yr[j];
              out[ob + (size_t)513 * NFR + f0 + j] = Yi[j];
            }
        }
      }
    }
  }
#undef BAR
}

extern "C" void kernel_launch(void* const* d_in, const int* in_sizes, int n_in,
                              void* d_out, int out_size, void* d_ws, size_t ws_size,
                              hipStream_t stream) {
  const float* x = (const float*)d_in[0];       // [8, 1048576] f32
  float* out = (float*)d_out;                   // [8, 1026, 4097] f32

  __hip_bfloat16* xpBf = (__hip_bfloat16*)d_ws;                 // NB*XP2 bf16
  __hip_bfloat16* cmat = xpBf + (size_t)NB * XP2;               // MPAD*256 bf16

  prep<<<NPREP, 256, 0, stream>>>(x, xpBf, cmat);
  stft_fgemm<<<NWG2, 512, 0, stream>>>(cmat, xpBf, out);
}